// Round 2
// baseline (1098.493 us; speedup 1.0000x reference)
//
#include <hip/hip_runtime.h>
#include <stdint.h>

#define B_TOT 131072

// ---------------- K0: prep ----------------
// WdhT[l][h] = W_dh[h][l]; bias3 = b_do + decoder_bias + pre_bias; sparsity = 5/64
__global__ void k_prep(const float* __restrict__ W_dh,
                       const float* __restrict__ b_do,
                       const float* __restrict__ dec_b,
                       const float* __restrict__ pre_bias,
                       float* __restrict__ WdhT,
                       float* __restrict__ bias3,
                       float* __restrict__ spars_out)
{
    int t = blockIdx.x * blockDim.x + threadIdx.x;
    for (int i = t; i < 512 * 64; i += gridDim.x * blockDim.x) {
        int h = i >> 6, l = i & 63;
        WdhT[l * 512 + h] = W_dh[i];
    }
    if (t < 256) bias3[t] = b_do[t] + dec_b[t] + pre_bias[t];
    if (t == 0) spars_out[0] = 5.0f / 64.0f;
}

// ---------------- K1: h = relu((x - pre_bias) @ W_eh^T + b_eh) ----------------
// grid (rows/64, 2), block 256. Tile: 64 rows x 256 cols, K=256 in 8 chunks of 32.
__global__ __launch_bounds__(256, 2)
void k_enc1(const float* __restrict__ x,        // already offset to chunk start
            const float* __restrict__ pre_bias,
            const float* __restrict__ W_eh,     // [512][256]
            const float* __restrict__ b_eh,     // [512]
            float* __restrict__ h)              // chunk-local [rows][512]
{
    __shared__ float sA[32][68];    // [k][r]
    __shared__ float sB[32][260];   // [k][c]
    const int t  = threadIdx.x;
    const int rb = blockIdx.x * 64;
    const int cb = blockIdx.y * 256;
    const int rg = t >> 5;          // 0..7
    const int cg = t & 31;          // 0..31
    const int r0 = rg * 8;
    const int ca = cg * 4;
    const int cbx = 128 + cg * 4;

    float acc[8][8];
    #pragma unroll
    for (int i = 0; i < 8; i++)
        #pragma unroll
        for (int j = 0; j < 8; j++) acc[i][j] = 0.0f;

    #pragma unroll 1
    for (int k0 = 0; k0 < 256; k0 += 32) {
        // stage x tile [64 r][32 k] -> sA[k][r], centered
        #pragma unroll
        for (int i = 0; i < 2; i++) {
            int f = t + i * 256;            // 0..511
            int r = f >> 3, k4 = f & 7;
            const float4 v  = *reinterpret_cast<const float4*>(&x[(size_t)(rb + r) * 256 + k0 + k4 * 4]);
            const float4 pb = *reinterpret_cast<const float4*>(&pre_bias[k0 + k4 * 4]);
            sA[k4 * 4 + 0][r] = v.x - pb.x;
            sA[k4 * 4 + 1][r] = v.y - pb.y;
            sA[k4 * 4 + 2][r] = v.z - pb.z;
            sA[k4 * 4 + 3][r] = v.w - pb.w;
        }
        // stage W_eh tile [256 c][32 k] -> sB[k][c]
        #pragma unroll
        for (int i = 0; i < 8; i++) {
            int f = t + i * 256;            // 0..2047
            int c = f >> 3, k4 = f & 7;
            const float4 v = *reinterpret_cast<const float4*>(&W_eh[(size_t)(cb + c) * 256 + k0 + k4 * 4]);
            sB[k4 * 4 + 0][c] = v.x;
            sB[k4 * 4 + 1][c] = v.y;
            sB[k4 * 4 + 2][c] = v.z;
            sB[k4 * 4 + 3][c] = v.w;
        }
        __syncthreads();
        #pragma unroll
        for (int kk = 0; kk < 32; kk++) {
            float4 a0 = *reinterpret_cast<const float4*>(&sA[kk][r0]);
            float4 a1 = *reinterpret_cast<const float4*>(&sA[kk][r0 + 4]);
            float4 b0 = *reinterpret_cast<const float4*>(&sB[kk][ca]);
            float4 b1 = *reinterpret_cast<const float4*>(&sB[kk][cbx]);
            float a[8]  = {a0.x, a0.y, a0.z, a0.w, a1.x, a1.y, a1.z, a1.w};
            float bb[8] = {b0.x, b0.y, b0.z, b0.w, b1.x, b1.y, b1.z, b1.w};
            #pragma unroll
            for (int i = 0; i < 8; i++)
                #pragma unroll
                for (int j = 0; j < 8; j++)
                    acc[i][j] = fmaf(a[i], bb[j], acc[i][j]);
        }
        __syncthreads();
    }
    // epilogue: relu(acc + b_eh) -> h
    #pragma unroll
    for (int i = 0; i < 8; i++) {
        size_t r = (size_t)(rb + r0 + i);
        #pragma unroll
        for (int half = 0; half < 2; half++) {
            int c = cb + (half ? cbx : ca);
            float4 o;
            o.x = fmaxf(acc[i][half * 4 + 0] + b_eh[c + 0], 0.0f);
            o.y = fmaxf(acc[i][half * 4 + 1] + b_eh[c + 1], 0.0f);
            o.z = fmaxf(acc[i][half * 4 + 2] + b_eh[c + 2], 0.0f);
            o.w = fmaxf(acc[i][half * 4 + 3] + b_eh[c + 3], 0.0f);
            *reinterpret_cast<float4*>(&h[r * 512 + c]) = o;
        }
    }
}

// ---------------- K2: pre_act = h @ W_eo^T + b_eo + latent_bias; top-5; outputs ----------------
// grid rows/64, block 256. Micro 4 rows x 4 latents/thread.
__global__ __launch_bounds__(256, 2)
void k_enc2_topk(const float* __restrict__ h,      // chunk-local [rows][512]
                 const float* __restrict__ W_eo,   // [64][512]
                 const float* __restrict__ b_eo,
                 const float* __restrict__ lat_b,
                 float* __restrict__ pre_out,      // global [B][64]
                 float* __restrict__ mask_out,     // global [B][64]
                 float* __restrict__ sl_out,       // global [B][64]
                 float* __restrict__ t5v,          // chunk-local [cap][5]
                 int*   __restrict__ t5i,          // chunk-local [cap][5]
                 int row0)
{
    __shared__ float sH[64][65];    // [k][r]
    __shared__ float sW[64][65];    // [k][l]
    __shared__ float pa[64][65];    // [r][l]
    __shared__ unsigned long long mbits[64];
    const int t  = threadIdx.x;
    const int rb = blockIdx.x * 64;
    const int rg = t >> 4, lg = t & 15;
    const int r0 = rg * 4, l0 = lg * 4;

    float acc[4][4];
    #pragma unroll
    for (int i = 0; i < 4; i++)
        #pragma unroll
        for (int j = 0; j < 4; j++) acc[i][j] = 0.0f;

    #pragma unroll 1
    for (int k0 = 0; k0 < 512; k0 += 64) {
        // stage h tile [64 r][64 k] -> sH[k][r]
        #pragma unroll
        for (int i = 0; i < 4; i++) {
            int f = t + i * 256;            // 0..1023
            int r = f >> 4, k4 = f & 15;
            const float4 v = *reinterpret_cast<const float4*>(&h[(size_t)(rb + r) * 512 + k0 + k4 * 4]);
            sH[k4 * 4 + 0][r] = v.x;
            sH[k4 * 4 + 1][r] = v.y;
            sH[k4 * 4 + 2][r] = v.z;
            sH[k4 * 4 + 3][r] = v.w;
        }
        // stage W_eo tile [64 l][64 k] -> sW[k][l]
        #pragma unroll
        for (int i = 0; i < 4; i++) {
            int f = t + i * 256;
            int l = f >> 4, k4 = f & 15;
            const float4 v = *reinterpret_cast<const float4*>(&W_eo[(size_t)l * 512 + k0 + k4 * 4]);
            sW[k4 * 4 + 0][l] = v.x;
            sW[k4 * 4 + 1][l] = v.y;
            sW[k4 * 4 + 2][l] = v.z;
            sW[k4 * 4 + 3][l] = v.w;
        }
        __syncthreads();
        float accC[4][4];
        #pragma unroll
        for (int i = 0; i < 4; i++)
            #pragma unroll
            for (int j = 0; j < 4; j++) accC[i][j] = 0.0f;
        #pragma unroll
        for (int kk = 0; kk < 64; kk++) {
            float a0 = sH[kk][r0 + 0], a1 = sH[kk][r0 + 1], a2 = sH[kk][r0 + 2], a3 = sH[kk][r0 + 3];
            float w0 = sW[kk][l0 + 0], w1 = sW[kk][l0 + 1], w2 = sW[kk][l0 + 2], w3 = sW[kk][l0 + 3];
            accC[0][0] = fmaf(a0, w0, accC[0][0]); accC[0][1] = fmaf(a0, w1, accC[0][1]);
            accC[0][2] = fmaf(a0, w2, accC[0][2]); accC[0][3] = fmaf(a0, w3, accC[0][3]);
            accC[1][0] = fmaf(a1, w0, accC[1][0]); accC[1][1] = fmaf(a1, w1, accC[1][1]);
            accC[1][2] = fmaf(a1, w2, accC[1][2]); accC[1][3] = fmaf(a1, w3, accC[1][3]);
            accC[2][0] = fmaf(a2, w0, accC[2][0]); accC[2][1] = fmaf(a2, w1, accC[2][1]);
            accC[2][2] = fmaf(a2, w2, accC[2][2]); accC[2][3] = fmaf(a2, w3, accC[2][3]);
            accC[3][0] = fmaf(a3, w0, accC[3][0]); accC[3][1] = fmaf(a3, w1, accC[3][1]);
            accC[3][2] = fmaf(a3, w2, accC[3][2]); accC[3][3] = fmaf(a3, w3, accC[3][3]);
        }
        #pragma unroll
        for (int i = 0; i < 4; i++)
            #pragma unroll
            for (int j = 0; j < 4; j++) acc[i][j] += accC[i][j];
        __syncthreads();
    }
    // bias, stage pre_act tile
    #pragma unroll
    for (int i = 0; i < 4; i++)
        #pragma unroll
        for (int j = 0; j < 4; j++)
            pa[r0 + i][l0 + j] = acc[i][j] + b_eo[l0 + j] + lat_b[l0 + j];
    __syncthreads();
    // top-5 per row (threads 0..63), tie -> lowest index (strict >)
    if (t < 64) {
        int r = t;
        unsigned long long used = 0ULL;
        float bv[5]; int bi[5];
        #pragma unroll
        for (int p = 0; p < 5; p++) {
            float best = -3.402823466e38f; int bidx = 0;
            for (int j = 0; j < 64; j++) {
                float v = pa[r][j];
                if (!((used >> j) & 1ULL) && v > best) { best = v; bidx = j; }
            }
            used |= 1ULL << bidx;
            bv[p] = best; bi[p] = bidx;
        }
        mbits[r] = used;
        size_t lr = (size_t)(rb + r);   // chunk-local
        #pragma unroll
        for (int p = 0; p < 5; p++) { t5v[lr * 5 + p] = bv[p]; t5i[lr * 5 + p] = bi[p]; }
    }
    __syncthreads();
    // coalesced writes of pre_act / mask / sparse_latent
    {
        int row = t >> 2, c0 = (t & 3) * 16;
        size_t gr = (size_t)(row0 + rb + row);
        unsigned long long bits = mbits[row];
        #pragma unroll
        for (int g = 0; g < 4; g++) {
            int c = c0 + g * 4;
            float p0 = pa[row][c + 0], p1 = pa[row][c + 1], p2 = pa[row][c + 2], p3 = pa[row][c + 3];
            float m0 = (float)((bits >> (c + 0)) & 1ULL);
            float m1 = (float)((bits >> (c + 1)) & 1ULL);
            float m2 = (float)((bits >> (c + 2)) & 1ULL);
            float m3 = (float)((bits >> (c + 3)) & 1ULL);
            float4 pv = {p0, p1, p2, p3};
            float4 mv = {m0, m1, m2, m3};
            float4 sv = {m0 * p0, m1 * p1, m2 * p2, m3 * p3};
            *reinterpret_cast<float4*>(&pre_out[gr * 64 + c])  = pv;
            *reinterpret_cast<float4*>(&mask_out[gr * 64 + c]) = mv;
            *reinterpret_cast<float4*>(&sl_out[gr * 64 + c])   = sv;
        }
    }
}

// ---------------- K3: recon = relu_hd @ W_do^T + bias3 (hd built on the fly) ----------------
// grid rows/64, block 256. hd[r][h] = relu(b_dh[h] + sum_5 val*WdhT[idx][h])
__global__ __launch_bounds__(256, 2)
void k_dec(const float* __restrict__ t5v, const int* __restrict__ t5i,   // chunk-local
           const float* __restrict__ WdhT,   // [64][512]
           const float* __restrict__ b_dh,   // [512]
           const float* __restrict__ W_do,   // [256][512]
           const float* __restrict__ bias3,  // [256]
           float* __restrict__ recon,        // global [B][256]
           int row0)
{
    __shared__ float sA[32][68];     // hd [k][r]
    __shared__ float sB[32][260];    // W_do [k][c]
    __shared__ float svv[64][5];
    __shared__ int   sii[64][5];
    const int t  = threadIdx.x;
    const int rb = blockIdx.x * 64;
    // 320 entries, 256 threads -> strided loop (BUGFIX vs prior round)
    for (int i = t; i < 320; i += 256) {
        int r = i / 5, p = i % 5;
        size_t lr = (size_t)(rb + r);
        svv[r][p] = t5v[lr * 5 + p];
        sii[r][p] = t5i[lr * 5 + p];
    }
    __syncthreads();

    const int rg = t >> 5, cg = t & 31;
    const int r0 = rg * 8;
    const int ca = cg * 4;
    const int cbx = 128 + cg * 4;

    float acc[8][8];
    #pragma unroll
    for (int i = 0; i < 8; i++)
        #pragma unroll
        for (int j = 0; j < 8; j++) acc[i][j] = 0.0f;

    #pragma unroll 1
    for (int k0 = 0; k0 < 512; k0 += 32) {
        // build hd chunk: thread covers h' = t&31, rows rB..rB+7
        {
            int hh = k0 + (t & 31);
            int rB = (t >> 5) * 8;
            float bdh = b_dh[hh];
            #pragma unroll
            for (int rr = 0; rr < 8; rr++) {
                int r = rB + rr;
                float a = bdh;
                #pragma unroll
                for (int p = 0; p < 5; p++)
                    a = fmaf(svv[r][p], WdhT[(size_t)sii[r][p] * 512 + hh], a);
                sA[t & 31][r] = fmaxf(a, 0.0f);
            }
        }
        // stage W_do tile [256 c][32 k] -> sB[k][c]
        #pragma unroll
        for (int i = 0; i < 8; i++) {
            int f = t + i * 256;
            int c = f >> 3, k4 = f & 7;
            const float4 v = *reinterpret_cast<const float4*>(&W_do[(size_t)c * 512 + k0 + k4 * 4]);
            sB[k4 * 4 + 0][c] = v.x;
            sB[k4 * 4 + 1][c] = v.y;
            sB[k4 * 4 + 2][c] = v.z;
            sB[k4 * 4 + 3][c] = v.w;
        }
        __syncthreads();
        #pragma unroll
        for (int kk = 0; kk < 32; kk++) {
            float4 a0 = *reinterpret_cast<const float4*>(&sA[kk][r0]);
            float4 a1 = *reinterpret_cast<const float4*>(&sA[kk][r0 + 4]);
            float4 b0 = *reinterpret_cast<const float4*>(&sB[kk][ca]);
            float4 b1 = *reinterpret_cast<const float4*>(&sB[kk][cbx]);
            float a[8]  = {a0.x, a0.y, a0.z, a0.w, a1.x, a1.y, a1.z, a1.w};
            float bb[8] = {b0.x, b0.y, b0.z, b0.w, b1.x, b1.y, b1.z, b1.w};
            #pragma unroll
            for (int i = 0; i < 8; i++)
                #pragma unroll
                for (int j = 0; j < 8; j++)
                    acc[i][j] = fmaf(a[i], bb[j], acc[i][j]);
        }
        __syncthreads();
    }
    // epilogue: acc + bias3 -> recon (no relu)
    #pragma unroll
    for (int i = 0; i < 8; i++) {
        size_t r = (size_t)(row0 + rb + r0 + i);
        #pragma unroll
        for (int half = 0; half < 2; half++) {
            int c = (half ? cbx : ca);
            float4 o;
            o.x = acc[i][half * 4 + 0] + bias3[c + 0];
            o.y = acc[i][half * 4 + 1] + bias3[c + 1];
            o.z = acc[i][half * 4 + 2] + bias3[c + 2];
            o.w = acc[i][half * 4 + 3] + bias3[c + 3];
            *reinterpret_cast<float4*>(&recon[r * 256 + c]) = o;
        }
    }
}

// ---------------- host ----------------
extern "C" void kernel_launch(void* const* d_in, const int* in_sizes, int n_in,
                              void* d_out, int out_size, void* d_ws, size_t ws_size,
                              hipStream_t stream)
{
    const float* x        = (const float*)d_in[0];
    const float* pre_bias = (const float*)d_in[1];
    const float* W_eh     = (const float*)d_in[2];
    const float* b_eh     = (const float*)d_in[3];
    const float* W_eo     = (const float*)d_in[4];
    const float* b_eo     = (const float*)d_in[5];
    const float* lat_b    = (const float*)d_in[6];
    const float* W_dh     = (const float*)d_in[7];
    const float* b_dh     = (const float*)d_in[8];
    const float* W_do     = (const float*)d_in[9];
    const float* b_do     = (const float*)d_in[10];
    const float* dec_b    = (const float*)d_in[11];

    float* out = (float*)d_out;
    float* recon_out = out;                               // B*256
    float* sl_out    = out + (size_t)B_TOT * 256;         // B*64
    float* pre_out   = sl_out + (size_t)B_TOT * 64;       // B*64
    float* mask_out  = pre_out + (size_t)B_TOT * 64;      // B*64
    float* spars_out = mask_out + (size_t)B_TOT * 64;     // 1

    // ws layout: WdhT (128KB) | bias3 (1KB) | t5v (cap*20) | t5i (cap*20) | hbuf (cap*2048)
    char* ws = (char*)d_ws;
    float* WdhT  = (float*)ws;
    float* bias3 = (float*)(ws + 131072);
    const size_t base = 132096;

    size_t avail = ws_size > base ? ws_size - base : 0;
    long long cap = (long long)(avail / 2088);            // 2048 (hbuf) + 40 (t5) bytes per row
    cap &= ~63LL;
    if (cap < 64) cap = 64;                               // below this ws is unusable anyway
    if (cap > B_TOT) cap = B_TOT;

    float* t5v  = (float*)(ws + base);
    int*   t5i  = (int*)  (ws + base + (size_t)cap * 20);
    float* hbuf = (float*)(ws + base + (size_t)cap * 40);

    k_prep<<<8, 256, 0, stream>>>(W_dh, b_do, dec_b, pre_bias, WdhT, bias3, spars_out);

    for (int r0 = 0; r0 < B_TOT; r0 += (int)cap) {
        int rows = B_TOT - r0 < (int)cap ? B_TOT - r0 : (int)cap;
        dim3 g1(rows / 64, 2);
        k_enc1<<<g1, 256, 0, stream>>>(x + (size_t)r0 * 256, pre_bias, W_eh, b_eh, hbuf);
        k_enc2_topk<<<rows / 64, 256, 0, stream>>>(hbuf, W_eo, b_eo, lat_b,
                                                   pre_out, mask_out, sl_out, t5v, t5i, r0);
        k_dec<<<rows / 64, 256, 0, stream>>>(t5v, t5i, WdhT, b_dh, W_do, bias3, recon_out, r0);
    }
}

// Round 3
// 820.405 us; speedup vs baseline: 1.3390x; 1.3390x over previous
//
#include <hip/hip_runtime.h>
#include <stdint.h>

#define B_TOT 131072

typedef short v8s __attribute__((ext_vector_type(8)));
typedef float v4f __attribute__((ext_vector_type(4)));

__device__ __forceinline__ unsigned short f2bf(float f) {
    union { float f; unsigned u; } v; v.f = f;
    unsigned u = v.u;
    u += 0x7fffu + ((u >> 16) & 1u);      // RNE
    return (unsigned short)(u >> 16);
}
__device__ __forceinline__ unsigned pack2(float lo, float hi) {
    return (unsigned)f2bf(lo) | ((unsigned)f2bf(hi) << 16);
}

// ---------------- K0: prep ----------------
// WdhT[l][h] = W_dh[h][l]; bias3 = b_do + dec_b + pre_bias; Wdo_frag = bf16 MFMA-B-fragment
// swizzle of W_do: frag[((nt*16+kc)*64+lane)*8+i] = bf16(W_do[nt*16+(lane&15)][kc*32+(lane>>4)*8+i])
__global__ void k_prep(const float* __restrict__ W_dh,
                       const float* __restrict__ b_do,
                       const float* __restrict__ dec_b,
                       const float* __restrict__ pre_bias,
                       const float* __restrict__ W_do,
                       float* __restrict__ WdhT,
                       float* __restrict__ bias3,
                       unsigned short* __restrict__ Wdo_frag,
                       float* __restrict__ spars_out)
{
    int t = blockIdx.x * blockDim.x + threadIdx.x;
    int nthr = gridDim.x * blockDim.x;
    for (int i = t; i < 512 * 64; i += nthr) {
        int h = i >> 6, l = i & 63;
        WdhT[l * 512 + h] = W_dh[i];
    }
    for (int g = t; g < 16384; g += nthr) {
        int lane = g & 63;
        int q = g >> 6;             // 0..255
        int nt = q >> 4, kc = q & 15;
        int col = nt * 16 + (lane & 15);
        int kbase = kc * 32 + (lane >> 4) * 8;
        const float* src = &W_do[(size_t)col * 512 + kbase];
        unsigned short* dst = &Wdo_frag[(size_t)g * 8];
        #pragma unroll
        for (int i = 0; i < 8; i++) dst[i] = f2bf(src[i]);
    }
    if (t < 256) bias3[t] = b_do[t] + dec_b[t] + pre_bias[t];
    if (t == 0) spars_out[0] = 5.0f / 64.0f;
}

// ---------------- K1: h = relu((x - pre_bias) @ W_eh^T + b_eh) ---------------- (unchanged fp32)
__global__ __launch_bounds__(256, 2)
void k_enc1(const float* __restrict__ x,
            const float* __restrict__ pre_bias,
            const float* __restrict__ W_eh,     // [512][256]
            const float* __restrict__ b_eh,
            float* __restrict__ h)              // chunk-local [rows][512]
{
    __shared__ float sA[32][68];
    __shared__ float sB[32][260];
    const int t  = threadIdx.x;
    const int rb = blockIdx.x * 64;
    const int cb = blockIdx.y * 256;
    const int rg = t >> 5;
    const int cg = t & 31;
    const int r0 = rg * 8;
    const int ca = cg * 4;
    const int cbx = 128 + cg * 4;

    float acc[8][8];
    #pragma unroll
    for (int i = 0; i < 8; i++)
        #pragma unroll
        for (int j = 0; j < 8; j++) acc[i][j] = 0.0f;

    #pragma unroll 1
    for (int k0 = 0; k0 < 256; k0 += 32) {
        #pragma unroll
        for (int i = 0; i < 2; i++) {
            int f = t + i * 256;
            int r = f >> 3, k4 = f & 7;
            const float4 v  = *reinterpret_cast<const float4*>(&x[(size_t)(rb + r) * 256 + k0 + k4 * 4]);
            const float4 pb = *reinterpret_cast<const float4*>(&pre_bias[k0 + k4 * 4]);
            sA[k4 * 4 + 0][r] = v.x - pb.x;
            sA[k4 * 4 + 1][r] = v.y - pb.y;
            sA[k4 * 4 + 2][r] = v.z - pb.z;
            sA[k4 * 4 + 3][r] = v.w - pb.w;
        }
        #pragma unroll
        for (int i = 0; i < 8; i++) {
            int f = t + i * 256;
            int c = f >> 3, k4 = f & 7;
            const float4 v = *reinterpret_cast<const float4*>(&W_eh[(size_t)(cb + c) * 256 + k0 + k4 * 4]);
            sB[k4 * 4 + 0][c] = v.x;
            sB[k4 * 4 + 1][c] = v.y;
            sB[k4 * 4 + 2][c] = v.z;
            sB[k4 * 4 + 3][c] = v.w;
        }
        __syncthreads();
        #pragma unroll
        for (int kk = 0; kk < 32; kk++) {
            float4 a0 = *reinterpret_cast<const float4*>(&sA[kk][r0]);
            float4 a1 = *reinterpret_cast<const float4*>(&sA[kk][r0 + 4]);
            float4 b0 = *reinterpret_cast<const float4*>(&sB[kk][ca]);
            float4 b1 = *reinterpret_cast<const float4*>(&sB[kk][cbx]);
            float a[8]  = {a0.x, a0.y, a0.z, a0.w, a1.x, a1.y, a1.z, a1.w};
            float bb[8] = {b0.x, b0.y, b0.z, b0.w, b1.x, b1.y, b1.z, b1.w};
            #pragma unroll
            for (int i = 0; i < 8; i++)
                #pragma unroll
                for (int j = 0; j < 8; j++)
                    acc[i][j] = fmaf(a[i], bb[j], acc[i][j]);
        }
        __syncthreads();
    }
    #pragma unroll
    for (int i = 0; i < 8; i++) {
        size_t r = (size_t)(rb + r0 + i);
        #pragma unroll
        for (int half = 0; half < 2; half++) {
            int c = cb + (half ? cbx : ca);
            float4 o;
            o.x = fmaxf(acc[i][half * 4 + 0] + b_eh[c + 0], 0.0f);
            o.y = fmaxf(acc[i][half * 4 + 1] + b_eh[c + 1], 0.0f);
            o.z = fmaxf(acc[i][half * 4 + 2] + b_eh[c + 2], 0.0f);
            o.w = fmaxf(acc[i][half * 4 + 3] + b_eh[c + 3], 0.0f);
            *reinterpret_cast<float4*>(&h[r * 512 + c]) = o;
        }
    }
}

// ---------------- K2: pre_act + top-5 + latent outputs ---------------- (unchanged fp32)
__global__ __launch_bounds__(256, 2)
void k_enc2_topk(const float* __restrict__ h,
                 const float* __restrict__ W_eo,
                 const float* __restrict__ b_eo,
                 const float* __restrict__ lat_b,
                 float* __restrict__ pre_out,
                 float* __restrict__ mask_out,
                 float* __restrict__ sl_out,
                 float* __restrict__ t5v,          // chunk-local [cap][5]
                 int*   __restrict__ t5i,
                 int row0)
{
    __shared__ float sH[64][65];
    __shared__ float sW[64][65];
    __shared__ float pa[64][65];
    __shared__ unsigned long long mbits[64];
    const int t  = threadIdx.x;
    const int rb = blockIdx.x * 64;
    const int rg = t >> 4, lg = t & 15;
    const int r0 = rg * 4, l0 = lg * 4;

    float acc[4][4];
    #pragma unroll
    for (int i = 0; i < 4; i++)
        #pragma unroll
        for (int j = 0; j < 4; j++) acc[i][j] = 0.0f;

    #pragma unroll 1
    for (int k0 = 0; k0 < 512; k0 += 64) {
        #pragma unroll
        for (int i = 0; i < 4; i++) {
            int f = t + i * 256;
            int r = f >> 4, k4 = f & 15;
            const float4 v = *reinterpret_cast<const float4*>(&h[(size_t)(rb + r) * 512 + k0 + k4 * 4]);
            sH[k4 * 4 + 0][r] = v.x;
            sH[k4 * 4 + 1][r] = v.y;
            sH[k4 * 4 + 2][r] = v.z;
            sH[k4 * 4 + 3][r] = v.w;
        }
        #pragma unroll
        for (int i = 0; i < 4; i++) {
            int f = t + i * 256;
            int l = f >> 4, k4 = f & 15;
            const float4 v = *reinterpret_cast<const float4*>(&W_eo[(size_t)l * 512 + k0 + k4 * 4]);
            sW[k4 * 4 + 0][l] = v.x;
            sW[k4 * 4 + 1][l] = v.y;
            sW[k4 * 4 + 2][l] = v.z;
            sW[k4 * 4 + 3][l] = v.w;
        }
        __syncthreads();
        float accC[4][4];
        #pragma unroll
        for (int i = 0; i < 4; i++)
            #pragma unroll
            for (int j = 0; j < 4; j++) accC[i][j] = 0.0f;
        #pragma unroll
        for (int kk = 0; kk < 64; kk++) {
            float a0 = sH[kk][r0 + 0], a1 = sH[kk][r0 + 1], a2 = sH[kk][r0 + 2], a3 = sH[kk][r0 + 3];
            float w0 = sW[kk][l0 + 0], w1 = sW[kk][l0 + 1], w2 = sW[kk][l0 + 2], w3 = sW[kk][l0 + 3];
            accC[0][0] = fmaf(a0, w0, accC[0][0]); accC[0][1] = fmaf(a0, w1, accC[0][1]);
            accC[0][2] = fmaf(a0, w2, accC[0][2]); accC[0][3] = fmaf(a0, w3, accC[0][3]);
            accC[1][0] = fmaf(a1, w0, accC[1][0]); accC[1][1] = fmaf(a1, w1, accC[1][1]);
            accC[1][2] = fmaf(a1, w2, accC[1][2]); accC[1][3] = fmaf(a1, w3, accC[1][3]);
            accC[2][0] = fmaf(a2, w0, accC[2][0]); accC[2][1] = fmaf(a2, w1, accC[2][1]);
            accC[2][2] = fmaf(a2, w2, accC[2][2]); accC[2][3] = fmaf(a2, w3, accC[2][3]);
            accC[3][0] = fmaf(a3, w0, accC[3][0]); accC[3][1] = fmaf(a3, w1, accC[3][1]);
            accC[3][2] = fmaf(a3, w2, accC[3][2]); accC[3][3] = fmaf(a3, w3, accC[3][3]);
        }
        #pragma unroll
        for (int i = 0; i < 4; i++)
            #pragma unroll
            for (int j = 0; j < 4; j++) acc[i][j] += accC[i][j];
        __syncthreads();
    }
    #pragma unroll
    for (int i = 0; i < 4; i++)
        #pragma unroll
        for (int j = 0; j < 4; j++)
            pa[r0 + i][l0 + j] = acc[i][j] + b_eo[l0 + j] + lat_b[l0 + j];
    __syncthreads();
    if (t < 64) {
        int r = t;
        unsigned long long used = 0ULL;
        float bv[5]; int bi[5];
        #pragma unroll
        for (int p = 0; p < 5; p++) {
            float best = -3.402823466e38f; int bidx = 0;
            for (int j = 0; j < 64; j++) {
                float v = pa[r][j];
                if (!((used >> j) & 1ULL) && v > best) { best = v; bidx = j; }
            }
            used |= 1ULL << bidx;
            bv[p] = best; bi[p] = bidx;
        }
        mbits[r] = used;
        size_t lr = (size_t)(rb + r);
        #pragma unroll
        for (int p = 0; p < 5; p++) { t5v[lr * 5 + p] = bv[p]; t5i[lr * 5 + p] = bi[p]; }
    }
    __syncthreads();
    {
        int row = t >> 2, c0 = (t & 3) * 16;
        size_t gr = (size_t)(row0 + rb + row);
        unsigned long long bits = mbits[row];
        #pragma unroll
        for (int g = 0; g < 4; g++) {
            int c = c0 + g * 4;
            float p0 = pa[row][c + 0], p1 = pa[row][c + 1], p2 = pa[row][c + 2], p3 = pa[row][c + 3];
            float m0 = (float)((bits >> (c + 0)) & 1ULL);
            float m1 = (float)((bits >> (c + 1)) & 1ULL);
            float m2 = (float)((bits >> (c + 2)) & 1ULL);
            float m3 = (float)((bits >> (c + 3)) & 1ULL);
            float4 pv = {p0, p1, p2, p3};
            float4 mv = {m0, m1, m2, m3};
            float4 sv = {m0 * p0, m1 * p1, m2 * p2, m3 * p3};
            *reinterpret_cast<float4*>(&pre_out[gr * 64 + c])  = pv;
            *reinterpret_cast<float4*>(&mask_out[gr * 64 + c]) = mv;
            *reinterpret_cast<float4*>(&sl_out[gr * 64 + c])   = sv;
        }
    }
}

// ---------------- K3: recon via bf16 MFMA ----------------
// Block: 256 thr = 4 waves; tile 64 rows x 256 cols; K=512 in 4 chunks of 128.
// hd chunk built fp32 -> bf16 into LDS (272B row stride = b128-floor bank pattern).
// Wave w covers cols [w*64, w*64+64): 4x4 tiles of 16x16x32 MFMA.
__global__ __launch_bounds__(256)
void k_dec(const float* __restrict__ t5v, const int* __restrict__ t5i,   // chunk-local
           const float* __restrict__ WdhT,        // [64][512] fp32
           const float* __restrict__ b_dh,        // [512]
           const unsigned short* __restrict__ Wdo_frag, // bf16 frag-swizzled
           const float* __restrict__ bias3,       // [256]
           float* __restrict__ recon,             // global [B][256]
           int row0)
{
    __shared__ __align__(16) short sA[64 * 136];  // 64 rows x 272B (128 bf16 + 8 pad)
    __shared__ float svv[64][5];
    __shared__ int   sii[64][5];
    const int t    = threadIdx.x;
    const int rb   = blockIdx.x * 64;
    const int lane = t & 63;
    const int w    = t >> 6;        // wave id = col group = build k-block
    const int r    = t & 63;        // build row

    for (int i = t; i < 320; i += 256) {
        int rr = i / 5, p = i % 5;
        size_t lr = (size_t)(rb + rr);
        svv[rr][p] = t5v[lr * 5 + p];
        sii[rr][p] = t5i[lr * 5 + p];
    }
    __syncthreads();

    v4f acc[4][4];
    #pragma unroll
    for (int i = 0; i < 4; i++)
        #pragma unroll
        for (int j = 0; j < 4; j++) acc[i][j] = (v4f){0.f, 0.f, 0.f, 0.f};

    #pragma unroll 1
    for (int c = 0; c < 4; ++c) {
        const int k0 = c * 128;
        // ---- build hd[r][k0 + w*32 .. +32) in fp32, relu, cvt bf16 -> sA ----
        {
            const int kbase = k0 + w * 32;
            float a[32];
            #pragma unroll
            for (int q = 0; q < 8; q++) {
                const float4 bd = *reinterpret_cast<const float4*>(&b_dh[kbase + q * 4]);
                a[q * 4 + 0] = bd.x; a[q * 4 + 1] = bd.y; a[q * 4 + 2] = bd.z; a[q * 4 + 3] = bd.w;
            }
            #pragma unroll
            for (int p = 0; p < 5; p++) {
                const float s = svv[r][p];
                const float4* wp = reinterpret_cast<const float4*>(&WdhT[(size_t)sii[r][p] * 512 + kbase]);
                #pragma unroll
                for (int q = 0; q < 8; q++) {
                    const float4 wv = wp[q];
                    a[q * 4 + 0] = fmaf(s, wv.x, a[q * 4 + 0]);
                    a[q * 4 + 1] = fmaf(s, wv.y, a[q * 4 + 1]);
                    a[q * 4 + 2] = fmaf(s, wv.z, a[q * 4 + 2]);
                    a[q * 4 + 3] = fmaf(s, wv.w, a[q * 4 + 3]);
                }
            }
            char* base = (char*)sA + r * 272 + w * 64;
            #pragma unroll
            for (int q2 = 0; q2 < 4; q2++) {
                uint4 o;
                o.x = pack2(fmaxf(a[q2 * 8 + 0], 0.f), fmaxf(a[q2 * 8 + 1], 0.f));
                o.y = pack2(fmaxf(a[q2 * 8 + 2], 0.f), fmaxf(a[q2 * 8 + 3], 0.f));
                o.z = pack2(fmaxf(a[q2 * 8 + 4], 0.f), fmaxf(a[q2 * 8 + 5], 0.f));
                o.w = pack2(fmaxf(a[q2 * 8 + 6], 0.f), fmaxf(a[q2 * 8 + 7], 0.f));
                *reinterpret_cast<uint4*>(base + q2 * 16) = o;
            }
        }
        __syncthreads();
        // ---- MFMA over this k-chunk ----
        #pragma unroll
        for (int kcl = 0; kcl < 4; ++kcl) {
            const int kcg = c * 4 + kcl;
            v8s af[4];
            #pragma unroll
            for (int mt = 0; mt < 4; mt++)
                af[mt] = *reinterpret_cast<const v8s*>(
                    (char*)sA + (mt * 16 + (lane & 15)) * 272 + kcl * 64 + (lane >> 4) * 16);
            v8s bf[4];
            #pragma unroll
            for (int ntl = 0; ntl < 4; ntl++) {
                const int ntg = w * 4 + ntl;
                bf[ntl] = *reinterpret_cast<const v8s*>(
                    Wdo_frag + ((size_t)(ntg * 16 + kcg) * 64 + lane) * 8);
            }
            #pragma unroll
            for (int mt = 0; mt < 4; mt++)
                #pragma unroll
                for (int ntl = 0; ntl < 4; ntl++)
                    acc[mt][ntl] = __builtin_amdgcn_mfma_f32_16x16x32_bf16(
                        af[mt], bf[ntl], acc[mt][ntl], 0, 0, 0);
        }
        __syncthreads();
    }
    // ---- epilogue: C/D layout col=lane&15, row=(lane>>4)*4+j ----
    #pragma unroll
    for (int ntl = 0; ntl < 4; ntl++) {
        const int col = w * 64 + ntl * 16 + (lane & 15);
        const float bz = bias3[col];
        #pragma unroll
        for (int mt = 0; mt < 4; mt++) {
            #pragma unroll
            for (int j = 0; j < 4; j++) {
                const size_t row = (size_t)(row0 + rb + mt * 16 + (lane >> 4) * 4 + j);
                recon[row * 256 + col] = acc[mt][ntl][j] + bz;
            }
        }
    }
}

// ---------------- host ----------------
extern "C" void kernel_launch(void* const* d_in, const int* in_sizes, int n_in,
                              void* d_out, int out_size, void* d_ws, size_t ws_size,
                              hipStream_t stream)
{
    const float* x        = (const float*)d_in[0];
    const float* pre_bias = (const float*)d_in[1];
    const float* W_eh     = (const float*)d_in[2];
    const float* b_eh     = (const float*)d_in[3];
    const float* W_eo     = (const float*)d_in[4];
    const float* b_eo     = (const float*)d_in[5];
    const float* lat_b    = (const float*)d_in[6];
    const float* W_dh     = (const float*)d_in[7];
    const float* b_dh     = (const float*)d_in[8];
    const float* W_do     = (const float*)d_in[9];
    const float* b_do     = (const float*)d_in[10];
    const float* dec_b    = (const float*)d_in[11];

    float* out = (float*)d_out;
    float* recon_out = out;
    float* sl_out    = out + (size_t)B_TOT * 256;
    float* pre_out   = sl_out + (size_t)B_TOT * 64;
    float* mask_out  = pre_out + (size_t)B_TOT * 64;
    float* spars_out = mask_out + (size_t)B_TOT * 64;

    // ws: WdhT 128KB | bias3 1KB | Wdo_frag 256KB | t5v cap*20 | t5i cap*20 | hbuf cap*2048
    char* ws = (char*)d_ws;
    float* WdhT            = (float*)ws;
    float* bias3           = (float*)(ws + 131072);
    unsigned short* WdoF   = (unsigned short*)(ws + 132096);
    const size_t base = 132096 + 262144;

    size_t avail = ws_size > base ? ws_size - base : 0;
    long long cap = (long long)(avail / 2088);
    cap &= ~63LL;
    if (cap < 64) cap = 64;
    if (cap > B_TOT) cap = B_TOT;

    float* t5v  = (float*)(ws + base);
    int*   t5i  = (int*)  (ws + base + (size_t)cap * 20);
    float* hbuf = (float*)(ws + base + (size_t)cap * 40);

    k_prep<<<16, 256, 0, stream>>>(W_dh, b_do, dec_b, pre_bias, W_do, WdhT, bias3, WdoF, spars_out);

    for (int r0 = 0; r0 < B_TOT; r0 += (int)cap) {
        int rows = B_TOT - r0 < (int)cap ? B_TOT - r0 : (int)cap;
        dim3 g1(rows / 64, 2);
        k_enc1<<<g1, 256, 0, stream>>>(x + (size_t)r0 * 256, pre_bias, W_eh, b_eh, hbuf);
        k_enc2_topk<<<rows / 64, 256, 0, stream>>>(hbuf, W_eo, b_eo, lat_b,
                                                   pre_out, mask_out, sl_out, t5v, t5i, r0);
        k_dec<<<rows / 64, 256, 0, stream>>>(t5v, t5i, WdhT, b_dh, WdoF, bias3, recon_out, r0);
    }
}

// Round 5
// 703.142 us; speedup vs baseline: 1.5623x; 1.1668x over previous
//
#include <hip/hip_runtime.h>
#include <stdint.h>

#define B_TOT 131072
#define GAP_TAU 2.5e-4f

typedef short v8s __attribute__((ext_vector_type(8)));
typedef float v4f __attribute__((ext_vector_type(4)));

__device__ __forceinline__ unsigned short f2bf(float f) {
    union { float f; unsigned u; } v; v.f = f;
    unsigned u = v.u;
    u += 0x7fffu + ((u >> 16) & 1u);      // RNE
    return (unsigned short)(u >> 16);
}
__device__ __forceinline__ float bf2f(unsigned short s) {
    union { unsigned u; float f; } v; v.u = ((unsigned)s) << 16;
    return v.f;
}
__device__ __forceinline__ unsigned pack2(float lo, float hi) {
    return (unsigned)f2bf(lo) | ((unsigned)f2bf(hi) << 16);
}

// ---------------- K0: prep ----------------
__global__ void k_prep(const float* __restrict__ W_dh,
                       const float* __restrict__ b_do,
                       const float* __restrict__ dec_b,
                       const float* __restrict__ pre_bias,
                       const float* __restrict__ W_do,
                       const float* __restrict__ W_eh,
                       const float* __restrict__ W_eo,
                       float* __restrict__ WdhT,
                       float* __restrict__ bias3,
                       unsigned short* __restrict__ Wdo_frag,
                       unsigned short* __restrict__ WehHi,
                       unsigned short* __restrict__ WehLo,
                       unsigned short* __restrict__ WeoHi,
                       unsigned short* __restrict__ WeoLo,
                       float* __restrict__ spars_out)
{
    int t = blockIdx.x * blockDim.x + threadIdx.x;
    int nthr = gridDim.x * blockDim.x;
    for (int i = t; i < 512 * 64; i += nthr) {
        int h = i >> 6, l = i & 63;
        WdhT[l * 512 + h] = W_dh[i];
    }
    // Wdo_frag (B-operand layout for k_dec), plain bf16
    for (int g = t; g < 16384; g += nthr) {
        int lane = g & 63;
        int q = g >> 6;
        int nt = q >> 4, kc = q & 15;
        int col = nt * 16 + (lane & 15);
        int kbase = kc * 32 + (lane >> 4) * 8;
        const float* src = &W_do[(size_t)col * 512 + kbase];
        unsigned short* dst = &Wdo_frag[(size_t)g * 8];
        #pragma unroll
        for (int i = 0; i < 8; i++) dst[i] = f2bf(src[i]);
    }
    // W_eh hi/lo frags: 32 ct x 8 kcg x 64 lanes
    for (int g = t; g < 32 * 8 * 64; g += nthr) {
        int lane = g & 63;
        int rem = g >> 6;
        int kcg = rem & 7, ct = rem >> 3;
        int c = ct * 16 + (lane & 15);
        int k = kcg * 32 + (lane >> 4) * 8;
        const float* src = &W_eh[(size_t)c * 256 + k];
        #pragma unroll
        for (int i = 0; i < 8; i++) {
            unsigned short hi = f2bf(src[i]);
            WehHi[(size_t)g * 8 + i] = hi;
            WehLo[(size_t)g * 8 + i] = f2bf(src[i] - bf2f(hi));
        }
    }
    // W_eo hi/lo frags: 4 lt x 16 kcg x 64 lanes
    for (int g = t; g < 4 * 16 * 64; g += nthr) {
        int lane = g & 63;
        int rem = g >> 6;
        int kcg = rem & 15, lt = rem >> 4;
        int l = lt * 16 + (lane & 15);
        int k = kcg * 32 + (lane >> 4) * 8;
        const float* src = &W_eo[(size_t)l * 512 + k];
        #pragma unroll
        for (int i = 0; i < 8; i++) {
            unsigned short hi = f2bf(src[i]);
            WeoHi[(size_t)g * 8 + i] = hi;
            WeoLo[(size_t)g * 8 + i] = f2bf(src[i] - bf2f(hi));
        }
    }
    if (t < 256) bias3[t] = b_do[t] + dec_b[t] + pre_bias[t];
    if (t == 0) spars_out[0] = 5.0f / 64.0f;
}

// ---------------- K1: h = relu((x-pre_bias) @ W_eh^T + b_eh), split-bf16 MFMA ----------------
__global__ __launch_bounds__(256, 3)
void k_enc1(const float* __restrict__ x,        // chunk-local [rows][256]
            const float* __restrict__ pre_bias,
            const unsigned short* __restrict__ WehHi,
            const unsigned short* __restrict__ WehLo,
            const float* __restrict__ b_eh,
            unsigned short* __restrict__ hHi,   // chunk-local [rows][512]
            unsigned short* __restrict__ hLo,
            int* __restrict__ fcount)
{
    if (blockIdx.x == 0 && blockIdx.y == 0 && threadIdx.x == 0) *fcount = 0;
    __shared__ __align__(16) unsigned short aH[4 * 64 * 8];
    __shared__ __align__(16) unsigned short aL[4 * 64 * 8];
    const int t    = threadIdx.x;
    const int lane = t & 63;
    const int w    = t >> 6;
    const int rb   = blockIdx.x * 64;
    const int cb   = blockIdx.y * 256;
    const int srow = t >> 2;
    const int skq  = t & 3;

    v4f acc[4][4];
    #pragma unroll
    for (int i = 0; i < 4; i++)
        #pragma unroll
        for (int j = 0; j < 4; j++) acc[i][j] = (v4f){0.f, 0.f, 0.f, 0.f};

    #pragma unroll 1
    for (int kc = 0; kc < 8; ++kc) {
        const int k0 = kc * 32;
        {
            const float4 v0 = *reinterpret_cast<const float4*>(&x[(size_t)(rb + srow) * 256 + k0 + skq * 8]);
            const float4 v1 = *reinterpret_cast<const float4*>(&x[(size_t)(rb + srow) * 256 + k0 + skq * 8 + 4]);
            const float4 p0 = *reinterpret_cast<const float4*>(&pre_bias[k0 + skq * 8]);
            const float4 p1 = *reinterpret_cast<const float4*>(&pre_bias[k0 + skq * 8 + 4]);
            float f[8] = {v0.x - p0.x, v0.y - p0.y, v0.z - p0.z, v0.w - p0.w,
                          v1.x - p1.x, v1.y - p1.y, v1.z - p1.z, v1.w - p1.w};
            unsigned hi2[4], lo2[4];
            #pragma unroll
            for (int q = 0; q < 4; q++) {
                unsigned short h0 = f2bf(f[q * 2]), h1 = f2bf(f[q * 2 + 1]);
                hi2[q] = (unsigned)h0 | ((unsigned)h1 << 16);
                lo2[q] = (unsigned)f2bf(f[q * 2] - bf2f(h0)) | ((unsigned)f2bf(f[q * 2 + 1] - bf2f(h1)) << 16);
            }
            const int mt = srow >> 4;
            const int ln = skq * 16 + (srow & 15);
            *reinterpret_cast<uint4*>(&aH[(mt * 64 + ln) * 8]) = *reinterpret_cast<uint4*>(hi2);
            *reinterpret_cast<uint4*>(&aL[(mt * 64 + ln) * 8]) = *reinterpret_cast<uint4*>(lo2);
        }
        __syncthreads();
        v8s wh[4], wl[4];
        #pragma unroll
        for (int ntl = 0; ntl < 4; ntl++) {
            const int ct = (cb >> 4) + w * 4 + ntl;
            const size_t idx = ((size_t)(ct * 8 + kc) * 64 + lane) * 8;
            wh[ntl] = *reinterpret_cast<const v8s*>(&WehHi[idx]);
            wl[ntl] = *reinterpret_cast<const v8s*>(&WehLo[idx]);
        }
        #pragma unroll
        for (int mt = 0; mt < 4; mt++) {
            const v8s ah = *reinterpret_cast<const v8s*>(&aH[(mt * 64 + lane) * 8]);
            const v8s al = *reinterpret_cast<const v8s*>(&aL[(mt * 64 + lane) * 8]);
            #pragma unroll
            for (int ntl = 0; ntl < 4; ntl++) {
                acc[mt][ntl] = __builtin_amdgcn_mfma_f32_16x16x32_bf16(wh[ntl], ah, acc[mt][ntl], 0, 0, 0);
                acc[mt][ntl] = __builtin_amdgcn_mfma_f32_16x16x32_bf16(wl[ntl], ah, acc[mt][ntl], 0, 0, 0);
                acc[mt][ntl] = __builtin_amdgcn_mfma_f32_16x16x32_bf16(wh[ntl], al, acc[mt][ntl], 0, 0, 0);
            }
        }
        __syncthreads();
    }
    #pragma unroll
    for (int mt = 0; mt < 4; mt++) {
        const size_t r = (size_t)(rb + mt * 16 + (lane & 15));
        #pragma unroll
        for (int ntl = 0; ntl < 4; ntl++) {
            const int c = cb + w * 64 + ntl * 16 + (lane >> 4) * 4;
            const float4 be = *reinterpret_cast<const float4*>(&b_eh[c]);
            float h0 = fmaxf(acc[mt][ntl][0] + be.x, 0.f);
            float h1 = fmaxf(acc[mt][ntl][1] + be.y, 0.f);
            float h2 = fmaxf(acc[mt][ntl][2] + be.z, 0.f);
            float h3 = fmaxf(acc[mt][ntl][3] + be.w, 0.f);
            unsigned short s0 = f2bf(h0), s1 = f2bf(h1), s2 = f2bf(h2), s3 = f2bf(h3);
            uint2 phi = { (unsigned)s0 | ((unsigned)s1 << 16), (unsigned)s2 | ((unsigned)s3 << 16) };
            uint2 plo = { (unsigned)f2bf(h0 - bf2f(s0)) | ((unsigned)f2bf(h1 - bf2f(s1)) << 16),
                          (unsigned)f2bf(h2 - bf2f(s2)) | ((unsigned)f2bf(h3 - bf2f(s3)) << 16) };
            *reinterpret_cast<uint2*>(&hHi[r * 512 + c]) = phi;
            *reinterpret_cast<uint2*>(&hLo[r * 512 + c]) = plo;
        }
    }
}

// ---------------- K2: pre_act (split-bf16 MFMA); top-5; gap-flag; outputs ----------------
__global__ __launch_bounds__(256, 4)
void k_enc2_topk(const unsigned short* __restrict__ hHi,
                 const unsigned short* __restrict__ hLo,
                 const unsigned short* __restrict__ WeoHi,
                 const unsigned short* __restrict__ WeoLo,
                 const float* __restrict__ b_eo,
                 const float* __restrict__ lat_b,
                 float* __restrict__ pre_out,
                 float* __restrict__ mask_out,
                 float* __restrict__ sl_out,
                 float* __restrict__ t5v,          // chunk-local [cap][5]
                 int*   __restrict__ t5i,
                 int*   __restrict__ fcount,
                 int*   __restrict__ flist,
                 int row0)
{
    __shared__ float pa[64][68];
    __shared__ unsigned long long mbits[64];
    const int t    = threadIdx.x;
    const int lane = t & 63;
    const int w    = t >> 6;
    const int rb   = blockIdx.x * 64;

    v4f acc[4];
    #pragma unroll
    for (int i = 0; i < 4; i++) acc[i] = (v4f){0.f, 0.f, 0.f, 0.f};

    #pragma unroll 1
    for (int kcl = 0; kcl < 16; ++kcl) {
        const size_t hoff = (size_t)(rb + w * 16 + (lane & 15)) * 512 + kcl * 32 + (lane >> 4) * 8;
        const v8s hh = *reinterpret_cast<const v8s*>(&hHi[hoff]);
        const v8s hl = *reinterpret_cast<const v8s*>(&hLo[hoff]);
        #pragma unroll
        for (int lt = 0; lt < 4; lt++) {
            const size_t idx = ((size_t)(lt * 16 + kcl) * 64 + lane) * 8;
            const v8s wh = *reinterpret_cast<const v8s*>(&WeoHi[idx]);
            const v8s wl = *reinterpret_cast<const v8s*>(&WeoLo[idx]);
            acc[lt] = __builtin_amdgcn_mfma_f32_16x16x32_bf16(wh, hh, acc[lt], 0, 0, 0);
            acc[lt] = __builtin_amdgcn_mfma_f32_16x16x32_bf16(wl, hh, acc[lt], 0, 0, 0);
            acc[lt] = __builtin_amdgcn_mfma_f32_16x16x32_bf16(wh, hl, acc[lt], 0, 0, 0);
        }
    }
    #pragma unroll
    for (int lt = 0; lt < 4; lt++) {
        const int l0 = lt * 16 + ((lane >> 4) << 2);
        const float4 be = *reinterpret_cast<const float4*>(&b_eo[l0]);
        const float4 lb = *reinterpret_cast<const float4*>(&lat_b[l0]);
        float4 o;
        o.x = acc[lt][0] + be.x + lb.x;
        o.y = acc[lt][1] + be.y + lb.y;
        o.z = acc[lt][2] + be.z + lb.z;
        o.w = acc[lt][3] + be.w + lb.w;
        *reinterpret_cast<float4*>(&pa[w * 16 + (lane & 15)][l0]) = o;
    }
    __syncthreads();
    // top-5 + 6th for gap check (threads 0..63)
    if (t < 64) {
        int r = t;
        unsigned long long used = 0ULL;
        float bv[5]; int bi[5];
        #pragma unroll
        for (int p = 0; p < 5; p++) {
            float best = -3.402823466e38f; int bidx = 0;
            for (int j = 0; j < 64; j++) {
                float v = pa[r][j];
                if (!((used >> j) & 1ULL) && v > best) { best = v; bidx = j; }
            }
            used |= 1ULL << bidx;
            bv[p] = best; bi[p] = bidx;
        }
        mbits[r] = used;
        size_t lr = (size_t)(rb + r);
        #pragma unroll
        for (int p = 0; p < 5; p++) { t5v[lr * 5 + p] = bv[p]; t5i[lr * 5 + p] = bi[p]; }
        // 6th max
        float v6 = -3.402823466e38f;
        for (int j = 0; j < 64; j++) {
            float v = pa[r][j];
            if (!((used >> j) & 1ULL) && v > v6) v6 = v;
        }
        if (bv[4] - v6 < GAP_TAU) {
            int slot = atomicAdd(fcount, 1);
            flist[slot] = rb + r;
        }
    }
    __syncthreads();
    {
        int row = t >> 2, c0 = (t & 3) * 16;
        size_t gr = (size_t)(row0 + rb + row);
        unsigned long long bits = mbits[row];
        #pragma unroll
        for (int g = 0; g < 4; g++) {
            int c = c0 + g * 4;
            float p0 = pa[row][c + 0], p1 = pa[row][c + 1], p2 = pa[row][c + 2], p3 = pa[row][c + 3];
            float m0 = (float)((bits >> (c + 0)) & 1ULL);
            float m1 = (float)((bits >> (c + 1)) & 1ULL);
            float m2 = (float)((bits >> (c + 2)) & 1ULL);
            float m3 = (float)((bits >> (c + 3)) & 1ULL);
            float4 pv = {p0, p1, p2, p3};
            float4 mv = {m0, m1, m2, m3};
            float4 sv = {m0 * p0, m1 * p1, m2 * p2, m3 * p3};
            *reinterpret_cast<float4*>(&pre_out[gr * 64 + c])  = pv;
            *reinterpret_cast<float4*>(&mask_out[gr * 64 + c]) = mv;
            *reinterpret_cast<float4*>(&sl_out[gr * 64 + c])   = sv;
        }
    }
}

// ---------------- K2b: fp32 exact repair of gap-flagged rows ----------------
// Fixed grid; loops over device-side list. Recomputes h and pre_act in fp32 from x,
// redoes top-5, overwrites the row's outputs and t5 entries.
__global__ __launch_bounds__(256)
void k_repair(const float* __restrict__ x,        // chunk-local
              const float* __restrict__ pre_bias,
              const float* __restrict__ W_eh,     // [512][256]
              const float* __restrict__ b_eh,
              const float* __restrict__ W_eo,     // [64][512]
              const float* __restrict__ b_eo,
              const float* __restrict__ lat_b,
              const int* __restrict__ fcount,
              const int* __restrict__ flist,
              float* __restrict__ pre_out,
              float* __restrict__ mask_out,
              float* __restrict__ sl_out,
              float* __restrict__ t5v,            // chunk-local
              int*   __restrict__ t5i,
              int row0)
{
    __shared__ float xs[256];
    __shared__ float hs[512];
    __shared__ float part[64][4];
    __shared__ float pav[64];
    __shared__ unsigned long long bitsS;
    const int t = threadIdx.x;
    const int n = *fcount;
    #pragma unroll 1
    for (int it = blockIdx.x; it < n; it += gridDim.x) {
        const int r = flist[it];
        xs[t] = x[(size_t)r * 256 + t] - pre_bias[t];
        __syncthreads();
        #pragma unroll 1
        for (int j = t; j < 512; j += 256) {
            const float* wr = &W_eh[(size_t)j * 256];
            float acc = 0.f;
            #pragma unroll
            for (int k = 0; k < 256; k += 4) {
                const float4 wv = *reinterpret_cast<const float4*>(&wr[k]);
                acc = fmaf(wv.x, xs[k + 0], acc);
                acc = fmaf(wv.y, xs[k + 1], acc);
                acc = fmaf(wv.z, xs[k + 2], acc);
                acc = fmaf(wv.w, xs[k + 3], acc);
            }
            hs[j] = fmaxf(acc + b_eh[j], 0.f);
        }
        __syncthreads();
        {
            const int l = t & 63, q = t >> 6;
            const float* wr = &W_eo[(size_t)l * 512 + q * 128];
            const float* hp = &hs[q * 128];
            float acc = 0.f;
            #pragma unroll
            for (int k = 0; k < 128; k += 4) {
                const float4 wv = *reinterpret_cast<const float4*>(&wr[k]);
                acc = fmaf(wv.x, hp[k + 0], acc);
                acc = fmaf(wv.y, hp[k + 1], acc);
                acc = fmaf(wv.z, hp[k + 2], acc);
                acc = fmaf(wv.w, hp[k + 3], acc);
            }
            part[l][q] = acc;
        }
        __syncthreads();
        if (t < 64)
            pav[t] = ((part[t][0] + part[t][1]) + (part[t][2] + part[t][3])) + b_eo[t] + lat_b[t];
        __syncthreads();
        if (t == 0) {
            unsigned long long used = 0ULL;
            const size_t lr = (size_t)r;
            #pragma unroll
            for (int p = 0; p < 5; p++) {
                float best = -3.402823466e38f; int bidx = 0;
                for (int j = 0; j < 64; j++) {
                    float v = pav[j];
                    if (!((used >> j) & 1ULL) && v > best) { best = v; bidx = j; }
                }
                used |= 1ULL << bidx;
                t5v[lr * 5 + p] = best; t5i[lr * 5 + p] = bidx;
            }
            bitsS = used;
        }
        __syncthreads();
        if (t < 64) {
            const size_t gr = (size_t)(row0 + r);
            const float v = pav[t];
            const float m = (float)((bitsS >> t) & 1ULL);
            pre_out[gr * 64 + t]  = v;
            mask_out[gr * 64 + t] = m;
            sl_out[gr * 64 + t]   = m * v;
        }
        __syncthreads();
    }
}

// ---------------- K3: recon via bf16 MFMA (unchanged, validated) ----------------
__global__ __launch_bounds__(256)
void k_dec(const float* __restrict__ t5v, const int* __restrict__ t5i,   // chunk-local
           const float* __restrict__ WdhT,        // [64][512] fp32
           const float* __restrict__ b_dh,
           const unsigned short* __restrict__ Wdo_frag,
           const float* __restrict__ bias3,
           float* __restrict__ recon,             // global [B][256]
           int row0)
{
    __shared__ __align__(16) short sA[64 * 136];
    __shared__ float svv[64][5];
    __shared__ int   sii[64][5];
    const int t    = threadIdx.x;
    const int rb   = blockIdx.x * 64;
    const int lane = t & 63;
    const int w    = t >> 6;
    const int r    = t & 63;

    for (int i = t; i < 320; i += 256) {
        int rr = i / 5, p = i % 5;
        size_t lr = (size_t)(rb + rr);
        svv[rr][p] = t5v[lr * 5 + p];
        sii[rr][p] = t5i[lr * 5 + p];
    }
    __syncthreads();

    v4f acc[4][4];
    #pragma unroll
    for (int i = 0; i < 4; i++)
        #pragma unroll
        for (int j = 0; j < 4; j++) acc[i][j] = (v4f){0.f, 0.f, 0.f, 0.f};

    #pragma unroll 1
    for (int c = 0; c < 4; ++c) {
        const int k0 = c * 128;
        {
            const int kbase = k0 + w * 32;
            float a[32];
            #pragma unroll
            for (int q = 0; q < 8; q++) {
                const float4 bd = *reinterpret_cast<const float4*>(&b_dh[kbase + q * 4]);
                a[q * 4 + 0] = bd.x; a[q * 4 + 1] = bd.y; a[q * 4 + 2] = bd.z; a[q * 4 + 3] = bd.w;
            }
            #pragma unroll
            for (int p = 0; p < 5; p++) {
                const float s = svv[r][p];
                const float4* wp = reinterpret_cast<const float4*>(&WdhT[(size_t)sii[r][p] * 512 + kbase]);
                #pragma unroll
                for (int q = 0; q < 8; q++) {
                    const float4 wv = wp[q];
                    a[q * 4 + 0] = fmaf(s, wv.x, a[q * 4 + 0]);
                    a[q * 4 + 1] = fmaf(s, wv.y, a[q * 4 + 1]);
                    a[q * 4 + 2] = fmaf(s, wv.z, a[q * 4 + 2]);
                    a[q * 4 + 3] = fmaf(s, wv.w, a[q * 4 + 3]);
                }
            }
            char* base = (char*)sA + r * 272 + w * 64;
            #pragma unroll
            for (int q2 = 0; q2 < 4; q2++) {
                uint4 o;
                o.x = pack2(fmaxf(a[q2 * 8 + 0], 0.f), fmaxf(a[q2 * 8 + 1], 0.f));
                o.y = pack2(fmaxf(a[q2 * 8 + 2], 0.f), fmaxf(a[q2 * 8 + 3], 0.f));
                o.z = pack2(fmaxf(a[q2 * 8 + 4], 0.f), fmaxf(a[q2 * 8 + 5], 0.f));
                o.w = pack2(fmaxf(a[q2 * 8 + 6], 0.f), fmaxf(a[q2 * 8 + 7], 0.f));
                *reinterpret_cast<uint4*>(base + q2 * 16) = o;
            }
        }
        __syncthreads();
        #pragma unroll
        for (int kcl = 0; kcl < 4; ++kcl) {
            const int kcg = c * 4 + kcl;
            v8s af[4];
            #pragma unroll
            for (int mt = 0; mt < 4; mt++)
                af[mt] = *reinterpret_cast<const v8s*>(
                    (char*)sA + (mt * 16 + (lane & 15)) * 272 + kcl * 64 + (lane >> 4) * 16);
            v8s bf[4];
            #pragma unroll
            for (int ntl = 0; ntl < 4; ntl++) {
                const int ntg = w * 4 + ntl;
                bf[ntl] = *reinterpret_cast<const v8s*>(
                    Wdo_frag + ((size_t)(ntg * 16 + kcg) * 64 + lane) * 8);
            }
            #pragma unroll
            for (int mt = 0; mt < 4; mt++)
                #pragma unroll
                for (int ntl = 0; ntl < 4; ntl++)
                    acc[mt][ntl] = __builtin_amdgcn_mfma_f32_16x16x32_bf16(
                        af[mt], bf[ntl], acc[mt][ntl], 0, 0, 0);
        }
        __syncthreads();
    }
    #pragma unroll
    for (int ntl = 0; ntl < 4; ntl++) {
        const int col = w * 64 + ntl * 16 + (lane & 15);
        const float bz = bias3[col];
        #pragma unroll
        for (int mt = 0; mt < 4; mt++) {
            #pragma unroll
            for (int j = 0; j < 4; j++) {
                const size_t row = (size_t)(row0 + rb + mt * 16 + (lane >> 4) * 4 + j);
                recon[row * 256 + col] = acc[mt][ntl][j] + bz;
            }
        }
    }
}

// ---------------- host ----------------
extern "C" void kernel_launch(void* const* d_in, const int* in_sizes, int n_in,
                              void* d_out, int out_size, void* d_ws, size_t ws_size,
                              hipStream_t stream)
{
    const float* x        = (const float*)d_in[0];
    const float* pre_bias = (const float*)d_in[1];
    const float* W_eh     = (const float*)d_in[2];
    const float* b_eh     = (const float*)d_in[3];
    const float* W_eo     = (const float*)d_in[4];
    const float* b_eo     = (const float*)d_in[5];
    const float* lat_b    = (const float*)d_in[6];
    const float* W_dh     = (const float*)d_in[7];
    const float* b_dh     = (const float*)d_in[8];
    const float* W_do     = (const float*)d_in[9];
    const float* b_do     = (const float*)d_in[10];
    const float* dec_b    = (const float*)d_in[11];

    float* out = (float*)d_out;
    float* recon_out = out;
    float* sl_out    = out + (size_t)B_TOT * 256;
    float* pre_out   = sl_out + (size_t)B_TOT * 64;
    float* mask_out  = pre_out + (size_t)B_TOT * 64;
    float* spars_out = mask_out + (size_t)B_TOT * 64;

    // ws: WdhT 128K | bias3 1K | WdoF 256K | WehHi 256K | WehLo 256K | WeoHi 64K | WeoLo 64K
    //     | fcount 64B | flist cap*4 | t5v cap*20 | t5i cap*20 | hHi cap*1024 | hLo cap*1024
    char* ws = (char*)d_ws;
    float* WdhT           = (float*)ws;
    float* bias3          = (float*)(ws + 131072);
    unsigned short* WdoF  = (unsigned short*)(ws + 132096);
    unsigned short* WehHi = (unsigned short*)(ws + 394240);
    unsigned short* WehLo = (unsigned short*)(ws + 656384);
    unsigned short* WeoHi = (unsigned short*)(ws + 918528);
    unsigned short* WeoLo = (unsigned short*)(ws + 984064);
    int* fcount           = (int*)(ws + 1049600);
    const size_t base = 1049664;

    size_t avail = ws_size > base ? ws_size - base : 0;
    long long cap = (long long)(avail / 2092);    // flist 4 + t5 40 + h planes 2048 per row
    cap &= ~63LL;
    if (cap < 64) cap = 64;
    if (cap > B_TOT) cap = B_TOT;

    int*   flist = (int*)  (ws + base);
    float* t5v   = (float*)(ws + base + (size_t)cap * 4);
    int*   t5i   = (int*)  (ws + base + (size_t)cap * 24);
    unsigned short* hHi = (unsigned short*)(ws + base + (size_t)cap * 44);
    unsigned short* hLo = hHi + (size_t)cap * 512;

    k_prep<<<32, 256, 0, stream>>>(W_dh, b_do, dec_b, pre_bias, W_do, W_eh, W_eo,
                                   WdhT, bias3, WdoF, WehHi, WehLo, WeoHi, WeoLo, spars_out);

    for (int r0 = 0; r0 < B_TOT; r0 += (int)cap) {
        int rows = B_TOT - r0 < (int)cap ? B_TOT - r0 : (int)cap;
        const float* xc = x + (size_t)r0 * 256;
        dim3 g1(rows / 64, 2);
        k_enc1<<<g1, 256, 0, stream>>>(xc, pre_bias, WehHi, WehLo, b_eh, hHi, hLo, fcount);
        k_enc2_topk<<<rows / 64, 256, 0, stream>>>(hHi, hLo, WeoHi, WeoLo, b_eo, lat_b,
                                                   pre_out, mask_out, sl_out, t5v, t5i,
                                                   fcount, flist, r0);
        k_repair<<<256, 256, 0, stream>>>(xc, pre_bias, W_eh, b_eh, W_eo, b_eo, lat_b,
                                          fcount, flist, pre_out, mask_out, sl_out,
                                          t5v, t5i, r0);
        k_dec<<<rows / 64, 256, 0, stream>>>(t5v, t5i, WdhT, b_dh, WdoF, bias3, recon_out, r0);
    }
}